// Round 4
// baseline (5783.492 us; speedup 1.0000x reference)
//
#include <hip/hip_runtime.h>

typedef unsigned short u16;

#define T_STEPS 128

__device__ __forceinline__ float bf2f(u16 h) {
  union { unsigned int u; float f; } v; v.u = ((unsigned int)h) << 16; return v.f;
}
__device__ __forceinline__ u16 f2bf(float f) {
  union { float f; unsigned int u; } v; v.f = f;
  unsigned int u = v.u;
  return (u16)((u + 0x7fffu + ((u >> 16) & 1u)) >> 16);
}
__device__ __forceinline__ unsigned int pack2(float a, float b) {
  return (unsigned int)f2bf(a) | ((unsigned int)f2bf(b) << 16);
}
__device__ __forceinline__ float clampf(float x, float lo, float hi) {
  return fmaxf(lo, fminf(x, hi));   // NaN-absorbing
}
__device__ __forceinline__ float tanh_fast(float x) {
  float e = __expf(2.0f * x);
  return 1.0f - 2.0f * __builtin_amdgcn_rcpf(e + 1.0f);
}

// dtype-templated scalar load
template<bool F32>
__device__ __forceinline__ float ldv(const void* p, size_t i) {
  if constexpr (F32) return ((const float*)p)[i];
  else               return bf2f(((const u16*)p)[i]);
}

#define SAT 131072.0f   // distinctive sanitizer clamp (bf16-exact; no-op for correct values)

template<bool F32>
__device__ __forceinline__ void egbody(
    const void* __restrict__ x, const void* __restrict__ target,
    const void* __restrict__ c0,
    const void* __restrict__ Wm0, const void* __restrict__ bm0,
    const void* __restrict__ Wm1, const void* __restrict__ bm1,
    const void* __restrict__ Wf10, const void* __restrict__ bf10,
    const void* __restrict__ Wf11, const void* __restrict__ bf11,
    const void* __restrict__ Wf20, const void* __restrict__ bf20,
    const void* __restrict__ Wf21, const void* __restrict__ bf21,
    const void* __restrict__ Wh0,  const void* __restrict__ bh0,
    const void* __restrict__ Wh1,  const void* __restrict__ bh1,
    void* __restrict__ out,
    float (&A1)[264][4], float (&A2)[264][4], float (&A3)[264][4],
    float (&S2)[768][4], float (&SMq)[32])
{
  const int f = threadIdx.x;          // feature index 0..255
  const int b0 = blockIdx.x << 2;     // first of 4 batch rows

  // hoisted biases
  const float bm0f  = ldv<F32>(bm0, f);
  const float bf10f = ldv<F32>(bf10, f);
  const float bf20f = ldv<F32>(bf20, f);
  const float bh0f  = ldv<F32>(bh0, f);
  const float bm1f  = ldv<F32>(bm1, f);

  // head assignment: 8 outputs x 32 partial threads
  const int ho  = f >> 5;
  const int sub = f & 31;
  const int colBase = (ho < 2) ? 0 : ((ho < 6) ? 256 : 512);

  // ---- init ----
#pragma unroll
  for (int b = 0; b < 4; ++b)
    A1[f][b] = ldv<F32>(c0, ((size_t)(b0 + b) << 8) + f);

  float s0v = 0.f, s1v = 0.f, s2v = 0.f, s3v = 0.f;
  float P[16];
#pragma unroll
  for (int i = 0; i < 16; ++i) P[i] = 0.f;
  if (f < 4) {
    const size_t bb = (size_t)(b0 + f);
    s0v = ldv<F32>(target, (bb << 9) + 0);
    s1v = ldv<F32>(target, (bb << 9) + 1);
    s2v = ldv<F32>(target, (bb << 9) + 2);
    s3v = ldv<F32>(target, (bb << 9) + 3);
    P[0] = P[5] = P[10] = P[15] = 1.f;
    const float i60 = 1.0f / 60.0f;
    A1[256][f] = s0v * i60; A1[257][f] = s1v * i60;
    A1[258][f] = s2v * i60; A1[259][f] = s3v * i60;
    A2[256][f] = s0v * i60; A2[257][f] = s1v * i60;
    A2[258][f] = s2v * i60; A2[259][f] = s3v * i60;
  }
  __syncthreads();

  for (int t = 0; t < T_STEPS; ++t) {
    if (f < 4) {
      const size_t xb = ((size_t)(b0 + f) << 8) + (t << 1);
      float m0 = ldv<F32>(x, xb)     * (1.0f / 60.0f);
      float m1 = ldv<F32>(x, xb + 1) * (1.0f / 60.0f);
      A2[260][f] = m0; A2[261][f] = m1;
      A3[256][f] = m0; A3[257][f] = m1;
    }
    // ---- stage1: cu = tanh(Wm0 . [c, sn]) ----
    {
      float a0 = bm0f, a1 = bm0f, a2 = bm0f, a3 = bm0f;
#pragma unroll 4
      for (int k = 0; k < 260; ++k) {
        float w = ldv<F32>(Wm0, k * 256 + f);
        float4 a = *(const float4*)&A1[k][0];
        a0 += w * a.x; a1 += w * a.y; a2 += w * a.z; a3 += w * a.w;
      }
      float4 cu;
      cu.x = tanh_fast(clampf(a0, -30.f, 30.f));
      cu.y = tanh_fast(clampf(a1, -30.f, 30.f));
      cu.z = tanh_fast(clampf(a2, -30.f, 30.f));
      cu.w = tanh_fast(clampf(a3, -30.f, 30.f));
      *(float4*)&A2[f][0] = cu;
      *(float4*)&A3[f][0] = cu;
    }
    __syncthreads();
    // ---- stage2: t1|t2|th ----
    {
      float t1a0 = bf10f, t1a1 = bf10f, t1a2 = bf10f, t1a3 = bf10f;
      float t2a0 = bf20f, t2a1 = bf20f, t2a2 = bf20f, t2a3 = bf20f;
      float tha0 = bh0f,  tha1 = bh0f,  tha2 = bh0f,  tha3 = bh0f;
#pragma unroll 2
      for (int k = 0; k < 260; ++k) {
        float w1 = ldv<F32>(Wf10, k * 256 + f);
        float w2 = ldv<F32>(Wf20, k * 256 + f);
        float w3 = ldv<F32>(Wh0,  k * 256 + f);
        float4 a = *(const float4*)&A2[k][0];
        t1a0 += w1 * a.x; t1a1 += w1 * a.y; t1a2 += w1 * a.z; t1a3 += w1 * a.w;
        t2a0 += w2 * a.x; t2a1 += w2 * a.y; t2a2 += w2 * a.z; t2a3 += w2 * a.w;
        tha0 += w3 * a.x; tha1 += w3 * a.y; tha2 += w3 * a.z; tha3 += w3 * a.w;
      }
#pragma unroll
      for (int k = 260; k < 262; ++k) {
        float w3 = ldv<F32>(Wh0, k * 256 + f);
        float4 a = *(const float4*)&A2[k][0];
        tha0 += w3 * a.x; tha1 += w3 * a.y; tha2 += w3 * a.z; tha3 += w3 * a.w;
      }
      float4 v;
      v.x = tanh_fast(clampf(t1a0, -30.f, 30.f));
      v.y = tanh_fast(clampf(t1a1, -30.f, 30.f));
      v.z = tanh_fast(clampf(t1a2, -30.f, 30.f));
      v.w = tanh_fast(clampf(t1a3, -30.f, 30.f));
      *(float4*)&S2[f][0] = v;
      v.x = tanh_fast(clampf(t2a0, -30.f, 30.f));
      v.y = tanh_fast(clampf(t2a1, -30.f, 30.f));
      v.z = tanh_fast(clampf(t2a2, -30.f, 30.f));
      v.w = tanh_fast(clampf(t2a3, -30.f, 30.f));
      *(float4*)&S2[256 + f][0] = v;
      v.x = tanh_fast(clampf(tha0, -30.f, 30.f));
      v.y = tanh_fast(clampf(tha1, -30.f, 30.f));
      v.z = tanh_fast(clampf(tha2, -30.f, 30.f));
      v.w = tanh_fast(clampf(tha3, -30.f, 30.f));
      *(float4*)&S2[512 + f][0] = v;
    }
    __syncthreads();
    // ---- small heads ----
    {
      float p0 = 0.f, p1 = 0.f, p2 = 0.f, p3 = 0.f;
#pragma unroll
      for (int i = 0; i < 8; ++i) {
        int k = sub + (i << 5);
        float w = (ho < 2) ? ldv<F32>(Wf11, (k << 1) + ho)
                : (ho < 6) ? ldv<F32>(Wf21, (k << 2) + (ho - 2))
                           : ldv<F32>(Wh1,  (k << 1) + (ho - 6));
        float4 a = *(const float4*)&S2[colBase + k][0];
        p0 += w * a.x; p1 += w * a.y; p2 += w * a.z; p3 += w * a.w;
      }
#pragma unroll
      for (int m = 1; m < 32; m <<= 1) {
        p0 += __shfl_xor(p0, m);
        p1 += __shfl_xor(p1, m);
        p2 += __shfl_xor(p2, m);
        p3 += __shfl_xor(p3, m);
      }
      if (sub == 0) {
        float hb = (ho < 2) ? ldv<F32>(bf11, ho)
                 : (ho < 6) ? ldv<F32>(bf21, ho - 2)
                            : ldv<F32>(bh1, ho - 6);
        float4 r;
        r.x = clampf(p0 + hb, -64.f, 64.f);
        r.y = clampf(p1 + hb, -64.f, 64.f);
        r.z = clampf(p2 + hb, -64.f, 64.f);
        r.w = clampf(p3 + hb, -64.f, 64.f);
        *(float4*)&SMq[ho << 2] = r;
      }
    }
    __syncthreads();
    // ---- Kalman update ----
    if (f < 4) {
      float d0  = SMq[0 * 4 + f], d1 = SMq[1 * 4 + f];
      float pv[4] = { SMq[2 * 4 + f], SMq[3 * 4 + f], SMq[4 * 4 + f], SMq[5 * 4 + f] };
      float hv0 = SMq[6 * 4 + f], hv1 = SMq[7 * 4 + f];
      const size_t xb = ((size_t)(b0 + f) << 8) + (t << 1);
      float m0 = ldv<F32>(x, xb);
      float m1 = ldv<F32>(x, xb + 1);
      float sp[4];
      sp[0] = s0v + s2v + 0.5f * d0;
      sp[1] = s1v + s3v + 0.5f * d1;
      sp[2] = s2v + d0;
      sp[3] = s3v + d1;
      float FP[16], Pp[16];
#pragma unroll
      for (int j = 0; j < 4; ++j) {
        FP[0 * 4 + j] = P[0 * 4 + j] + P[2 * 4 + j];
        FP[1 * 4 + j] = P[1 * 4 + j] + P[3 * 4 + j];
        FP[2 * 4 + j] = P[2 * 4 + j];
        FP[3 * 4 + j] = P[3 * 4 + j];
      }
#pragma unroll
      for (int i = 0; i < 4; ++i) {
        Pp[i * 4 + 0] = FP[i * 4 + 0] + FP[i * 4 + 2];
        Pp[i * 4 + 1] = FP[i * 4 + 1] + FP[i * 4 + 3];
        Pp[i * 4 + 2] = FP[i * 4 + 2];
        Pp[i * 4 + 3] = FP[i * 4 + 3];
      }
#pragma unroll
      for (int i = 0; i < 4; ++i)
#pragma unroll
        for (int j = 0; j < 4; ++j) Pp[i * 4 + j] += pv[i] * pv[j];
#pragma unroll
      for (int i = 0; i < 4; ++i) Pp[i * 4 + i] += 0.01f;
      float in0 = m0 - sp[0], in1 = m1 - sp[1];
      float S00 = Pp[0] + hv0 * hv0 + 1.0f;
      float S01 = Pp[1] + hv0 * hv1;
      float S10 = Pp[4] + hv1 * hv0;
      float S11 = Pp[5] + hv1 * hv1 + 1.0f;
      float det = S00 * S11 - S01 * S10;
      if (!(fabsf(det) > 1e-8f)) det = 1e-8f;
      float idet = 1.0f / det;
      float i00 =  S11 * idet, i01 = -S01 * idet, i10 = -S10 * idet, i11 = S00 * idet;
      float K[8], KS[8], su[4];
#pragma unroll
      for (int i = 0; i < 4; ++i) {
        K[i * 2 + 0] = Pp[i * 4 + 0] * i00 + Pp[i * 4 + 1] * i10;
        K[i * 2 + 1] = Pp[i * 4 + 0] * i01 + Pp[i * 4 + 1] * i11;
      }
#pragma unroll
      for (int i = 0; i < 4; ++i)
        su[i] = clampf(sp[i] + K[i * 2 + 0] * in0 + K[i * 2 + 1] * in1, -SAT, SAT);
#pragma unroll
      for (int i = 0; i < 4; ++i) {
        KS[i * 2 + 0] = K[i * 2 + 0] * S00 + K[i * 2 + 1] * S10;
        KS[i * 2 + 1] = K[i * 2 + 0] * S01 + K[i * 2 + 1] * S11;
      }
#pragma unroll
      for (int i = 0; i < 4; ++i)
#pragma unroll
        for (int j = 0; j < 4; ++j)
          P[i * 4 + j] = clampf(
              Pp[i * 4 + j] - (KS[i * 2 + 0] * K[j * 2 + 0] + KS[i * 2 + 1] * K[j * 2 + 1]),
              -SAT, SAT);
      s0v = su[0]; s1v = su[1]; s2v = su[2]; s3v = su[3];
      // ---- output s_upd, dtype-matched ----
      const size_t ob = ((size_t)(b0 + f) << 9) + (t << 2);
      if constexpr (F32) {
        float4 ov; ov.x = su[0]; ov.y = su[1]; ov.z = su[2]; ov.w = su[3];
        *(float4*)((float*)out + ob) = ov;
      } else {
        uint2 ov; ov.x = pack2(su[0], su[1]); ov.y = pack2(su[2], su[3]);
        *(uint2*)((u16*)out + ob) = ov;
      }
      const float i60 = 1.0f / 60.0f;
      A1[256][f] = su[0] * i60; A1[257][f] = su[1] * i60;
      A1[258][f] = su[2] * i60; A1[259][f] = su[3] * i60;
      A2[256][f] = su[0] * i60; A2[257][f] = su[1] * i60;
      A2[258][f] = su[2] * i60; A2[259][f] = su[3] * i60;
      A3[258][f] = su[0] * i60; A3[259][f] = su[1] * i60;
      A3[260][f] = su[2] * i60; A3[261][f] = su[3] * i60;
    }
    __syncthreads();
    // ---- stage3: c_new ----
    {
      float a0 = bm1f, a1 = bm1f, a2 = bm1f, a3 = bm1f;
#pragma unroll 4
      for (int k = 0; k < 262; ++k) {
        float w = ldv<F32>(Wm1, k * 256 + f);
        float4 a = *(const float4*)&A3[k][0];
        a0 += w * a.x; a1 += w * a.y; a2 += w * a.z; a3 += w * a.w;
      }
      float4 cn;
      cn.x = tanh_fast(clampf(a0, -30.f, 30.f));
      cn.y = tanh_fast(clampf(a1, -30.f, 30.f));
      cn.z = tanh_fast(clampf(a2, -30.f, 30.f));
      cn.w = tanh_fast(clampf(a3, -30.f, 30.f));
      *(float4*)&A1[f][0] = cn;
    }
    __syncthreads();
  }
}

// 512 blocks x 256 threads; each block owns 4 batch rows.
__global__ __launch_bounds__(256) void egbrnn_adaptive(
    const void* __restrict__ x, const void* __restrict__ target,
    const void* __restrict__ c0,
    const void* __restrict__ Wm0, const void* __restrict__ bm0,
    const void* __restrict__ Wm1, const void* __restrict__ bm1,
    const void* __restrict__ Wf10, const void* __restrict__ bf10,
    const void* __restrict__ Wf11, const void* __restrict__ bf11,
    const void* __restrict__ Wf20, const void* __restrict__ bf20,
    const void* __restrict__ Wf21, const void* __restrict__ bf21,
    const void* __restrict__ Wh0,  const void* __restrict__ bh0,
    const void* __restrict__ Wh1,  const void* __restrict__ bh1,
    void* __restrict__ out)
{
  __shared__ __align__(16) float A1[264][4];
  __shared__ __align__(16) float A2[264][4];
  __shared__ __align__(16) float A3[264][4];
  __shared__ __align__(16) float S2[768][4];
  __shared__ __align__(16) float SMq[32];

  // ---- dtype sniff: if x holds f32, its even u16 halves are mantissa bits,
  // which as bf16 reach >=2^17 w.p. ~1 over 256 samples; bf16 x stays <512. ----
  bool f32mode;
  {
    const u16* xu = (const u16*)x;
    float mx = 0.f;
    for (int i = 0; i < 256; ++i)
      mx = fmaxf(mx, fabsf(bf2f(xu[i << 1])));
    f32mode = (mx > 65536.f);
  }

  if (f32mode)
    egbody<true >(x, target, c0, Wm0, bm0, Wm1, bm1, Wf10, bf10, Wf11, bf11,
                  Wf20, bf20, Wf21, bf21, Wh0, bh0, Wh1, bh1, out,
                  A1, A2, A3, S2, SMq);
  else
    egbody<false>(x, target, c0, Wm0, bm0, Wm1, bm1, Wf10, bf10, Wf11, bf11,
                  Wf20, bf20, Wf21, bf21, Wh0, bh0, Wh1, bh1, out,
                  A1, A2, A3, S2, SMq);
}

extern "C" void kernel_launch(void* const* d_in, const int* in_sizes, int n_in,
                              void* d_out, int out_size, void* d_ws, size_t ws_size,
                              hipStream_t stream) {
  egbrnn_adaptive<<<dim3(512), dim3(256), 0, stream>>>(
      d_in[0], d_in[1], d_in[2],
      d_in[3], d_in[4], d_in[5], d_in[6],
      d_in[7], d_in[8], d_in[9], d_in[10],
      d_in[11], d_in[12], d_in[13], d_in[14],
      d_in[15], d_in[16], d_in[17], d_in[18],
      d_out);
}

// Round 5
// 1674.552 us; speedup vs baseline: 3.4538x; 3.4538x over previous
//
#include <hip/hip_runtime.h>

typedef unsigned short u16;
typedef __bf16 bf16x8 __attribute__((ext_vector_type(8)));
typedef float  f32x4  __attribute__((ext_vector_type(4)));

#define T_STEPS 128
#define KSTR    296   // ACT row stride (u16 elems): 288 logical + pad (148 dwords -> 2-way-bank-free)
#define S2STR   792   // stage2 output row stride (396 dwords -> 2-way-bank-free)

// ---- ws element-offset layout (u16 elements unless noted) ----
// PK1  @      0 : 16 ftiles * 9 kt * 512 = 73728   (Wm0 -> bf16 A-frags)
// PK2  @  73728 : 48 * 9 * 512          = 221184   (Wf10|Wf20|Wh0)
// PK3  @ 294912 : 16 * 9 * 512          = 73728    (Wm1, rows permuted to ACT2 layout)
// BIAS @ 368640 : 1288 floats = 2576 u16 (B1[256] B2[768] B3[256] BS[8])
// HW   @ 371216 : 8 * 256 = 2048        (head weights transposed [o][k], bf16)

__device__ __forceinline__ float bf2f(u16 h) {
  union { unsigned int u; float f; } v; v.u = ((unsigned int)h) << 16; return v.f;
}
__device__ __forceinline__ u16 f2bf(float f) {
  union { float f; unsigned int u; } v; v.f = f;
  unsigned int u = v.u;
  return (u16)((u + 0x7fffu + ((u >> 16) & 1u)) >> 16);
}
__device__ __forceinline__ unsigned int pack2(float a, float b) {
  return (unsigned int)f2bf(a) | ((unsigned int)f2bf(b) << 16);
}
__device__ __forceinline__ float clampf(float x, float lo, float hi) {
  return fmaxf(lo, fminf(x, hi));   // NaN-absorbing insurance; no-op for correct values
}
__device__ __forceinline__ float tanh_fast(float x) {
  float e = __expf(2.0f * x);
  return 1.0f - 2.0f * __builtin_amdgcn_rcpf(e + 1.0f);
}

// ---------------- weight repack: f32 -> bf16 MFMA A-fragments (runs every call) ----------------
__global__ void egbrnn_prep(
    const float* __restrict__ Wm0, const float* __restrict__ Wm1,
    const float* __restrict__ Wf10, const float* __restrict__ Wf11,
    const float* __restrict__ Wf20, const float* __restrict__ Wf21,
    const float* __restrict__ Wh0, const float* __restrict__ Wh1,
    const float* __restrict__ bm0, const float* __restrict__ bm1,
    const float* __restrict__ bf10, const float* __restrict__ bf11,
    const float* __restrict__ bf20, const float* __restrict__ bf21,
    const float* __restrict__ bh0, const float* __restrict__ bh1,
    u16* __restrict__ ws)
{
  int idx = blockIdx.x * 256 + threadIdx.x;
  // ---- PK1: Wm0, K rows: [c 0-255, sn 256-259], pad->288 ----
  if (idx < 73728) {
    int tile = idx >> 9, r = idx & 511;
    int lane = r >> 3, j = r & 7;
    int ft = tile / 9, kt = tile - ft * 9;
    int m = (ft << 4) + (lane & 15);
    int k = (kt << 5) + ((lane >> 4) << 3) + j;
    ws[idx] = (k < 260) ? f2bf(Wm0[k * 256 + m]) : (u16)0;
    return;
  }
  idx -= 73728;
  // ---- PK2: [Wf10 | Wf20 | Wh0], ACT2 K layout [cu 0-255, sn 256-259, meas/60 260-261, pad] ----
  if (idx < 221184) {
    int tile = idx >> 9, r = idx & 511;
    int lane = r >> 3, j = r & 7;
    int ft = tile / 9, kt = tile - ft * 9;
    int F = (ft << 4) + (lane & 15);
    int k = (kt << 5) + ((lane >> 4) << 3) + j;
    int sel = F >> 8, col = F & 255;
    u16 v = 0;
    if (sel == 0)      { if (k < 260) v = f2bf(Wf10[k * 256 + col]); }
    else if (sel == 1) { if (k < 260) v = f2bf(Wf20[k * 256 + col]); }
    else               { if (k < 262) v = f2bf(Wh0 [k * 256 + col]); }
    ws[73728 + idx] = v;
    return;
  }
  idx -= 221184;
  // ---- PK3: Wm1 rows permuted to ACT2 layout: k<256->cu; k 260,261->meas rows 256,257; k 264..267->supd rows 258..261 ----
  if (idx < 73728) {
    int tile = idx >> 9, r = idx & 511;
    int lane = r >> 3, j = r & 7;
    int ft = tile / 9, kt = tile - ft * 9;
    int m = (ft << 4) + (lane & 15);
    int k = (kt << 5) + ((lane >> 4) << 3) + j;
    int row = -1;
    if (k < 256) row = k;
    else if (k == 260 || k == 261) row = 256 + (k - 260);
    else if (k >= 264 && k < 268)  row = 258 + (k - 264);
    ws[294912 + idx] = (row >= 0) ? f2bf(Wm1[row * 256 + m]) : (u16)0;
    return;
  }
  idx -= 73728;
  // ---- biases (fp32, stored directly) ----
  if (idx < 1288) {
    float* BIAS = (float*)(ws + 368640);
    float h;
    if (idx < 256) h = bm0[idx];
    else if (idx < 1024) {
      int f = idx - 256;
      h = (f < 256) ? bf10[f] : (f < 512 ? bf20[f - 256] : bh0[f - 512]);
    } else if (idx < 1280) h = bm1[idx - 1024];
    else {
      int i2 = idx - 1280;
      h = (i2 < 2) ? bf11[i2] : (i2 < 6 ? bf21[i2 - 2] : bh1[i2 - 6]);
    }
    BIAS[idx] = h;
    return;
  }
  idx -= 1288;
  // ---- head weights transposed [o][k], bf16 ----
  if (idx < 2048) {
    int o = idx >> 8, k = idx & 255;
    float v;
    if (o < 2)      v = Wf11[k * 2 + o];
    else if (o < 6) v = Wf21[k * 4 + (o - 2)];
    else            v = Wh1[k * 2 + (o - 6)];
    ws[371216 + idx] = f2bf(v);
  }
}

// ---------------- one MFMA stage: out[f][b] = tanh(sum_k W[k][f]*actIn[b][k] + bias[f]) ----------------
// A-frag: A[m=lane&15][k=(lane>>4)*8+j] ; B-frag: B[k=(lane>>4)*8+j][n=lane&15]
// D: row=(lane>>4)*4+reg, col=lane&15  (m89/m91-verified layouts)
template<int NFT, int NKT>
__device__ __forceinline__ void stage_mm(
    const u16* __restrict__ pk, const float* __restrict__ bias,
    const u16* __restrict__ actIn, int inStride,
    u16* __restrict__ actOut, int outStride,
    int ft0, int ftStep, int lane)
{
  const int nidx = lane & 15;
  const int q = lane >> 4;
  f32x4 acc[NFT];
#pragma unroll
  for (int i = 0; i < NFT; ++i) { f32x4 z = {0.f, 0.f, 0.f, 0.f}; acc[i] = z; }
  const u16* bbase = actIn + nidx * inStride + (q << 3);
#pragma unroll 3
  for (int kt = 0; kt < NKT; ++kt) {
    bf16x8 bf = *(const bf16x8*)(bbase + (kt << 5));
#pragma unroll
    for (int i = 0; i < NFT; ++i) {
      const int ft = ft0 + i * ftStep;
      bf16x8 af = *(const bf16x8*)(pk + (((ft * NKT) + kt) << 9) + (lane << 3));
      acc[i] = __builtin_amdgcn_mfma_f32_16x16x32_bf16(af, bf, acc[i], 0, 0, 0);
    }
  }
#pragma unroll
  for (int i = 0; i < NFT; ++i) {
    const int ft = ft0 + i * ftStep;
    const int f0 = (ft << 4) + (q << 2);
    const float4 bs = *(const float4*)(bias + f0);
    float v0 = tanh_fast(clampf(acc[i][0] + bs.x, -30.f, 30.f));
    float v1 = tanh_fast(clampf(acc[i][1] + bs.y, -30.f, 30.f));
    float v2 = tanh_fast(clampf(acc[i][2] + bs.z, -30.f, 30.f));
    float v3 = tanh_fast(clampf(acc[i][3] + bs.w, -30.f, 30.f));
    uint2 pv; pv.x = pack2(v0, v1); pv.y = pack2(v2, v3);
    *(uint2*)(actOut + nidx * outStride + f0) = pv;
  }
}

// ---------------- main recurrent kernel: 128 blocks x 512 threads, 16 batch rows per block ----------------
// 128 blocks ~ 1 block/CU on half the chip; weights stream from L2 (~666 KB/step/block) = expected bound.
__global__ __launch_bounds__(512, 1) void egbrnn_main(
    const float* __restrict__ x, const float* __restrict__ target,
    const float* __restrict__ c0, const u16* __restrict__ wsp,
    float* __restrict__ out)
{
  __shared__ __align__(16) u16 ACT1[16 * KSTR];  // [b][k]: 0-255 c, 256-259 sn, pad
  __shared__ __align__(16) u16 ACT2[16 * KSTR];  // [b][k]: 0-255 cu, 256-259 sn, 260-261 meas/60, 264-267 supd/60
  __shared__ __align__(16) u16 S2O [16 * S2STR]; // [b][f]: 0-255 t1, 256-511 t2, 512-767 th
  __shared__ __align__(16) u16 HWs [8 * 256];    // head weights [o][k]
  __shared__ __align__(16) float SM[16 * 8];     // [b][o]: d0 d1 pv0..3 hv0 hv1

  const u16* PK1 = wsp;
  const u16* PK2 = wsp + 73728;
  const u16* PK3 = wsp + 294912;
  const float* BIAS = (const float*)(wsp + 368640);
  const float* B1 = BIAS;
  const float* B2 = BIAS + 256;
  const float* B3 = BIAS + 1024;
  const float* BS = BIAS + 1280;

  const int tid = threadIdx.x;
  const int wave = tid >> 6;
  const int lane = tid & 63;
  const int b0 = blockIdx.x << 4;

  // zero pad cols 256..295 of ACT1/ACT2
  for (int i = tid; i < 16 * (KSTR - 256); i += 512) {
    int b = i / (KSTR - 256), k = 256 + (i - b * (KSTR - 256));
    ACT1[b * KSTR + k] = 0; ACT2[b * KSTR + k] = 0;
  }
  // head weights -> LDS
  for (int i = tid; i < 2048; i += 512) HWs[i] = wsp[371216 + i];
  // c0 (f32) -> ACT1 bf16
  for (int i = tid; i < 16 * 256; i += 512) {
    int b = i >> 8, k = i & 255;
    ACT1[b * KSTR + k] = f2bf(c0[((size_t)(b0 + b) << 8) + k]);
  }
  float s0v = 0.f, s1v = 0.f, s2v = 0.f, s3v = 0.f;
  float P[16];
#pragma unroll
  for (int i = 0; i < 16; ++i) P[i] = 0.f;
  if (tid < 16) {
    const size_t bb = (size_t)(b0 + tid);
    float4 tg = *(const float4*)(target + (bb << 9));
    s0v = tg.x; s1v = tg.y; s2v = tg.z; s3v = tg.w;
    P[0] = P[5] = P[10] = P[15] = 1.f;
    const float i60 = 1.0f / 60.0f;
    uint2 snp; snp.x = pack2(s0v * i60, s1v * i60); snp.y = pack2(s2v * i60, s3v * i60);
    *(uint2*)(ACT1 + tid * KSTR + 256) = snp;
    *(uint2*)(ACT2 + tid * KSTR + 256) = snp;
  }
  __syncthreads();

  // head assignment: pair = (o,b); 4 partial lanes per pair (same quad, same wave)
  const int hpair = tid >> 2, hpart = tid & 3;
  const int hb = hpair & 15, ho = hpair >> 4;
  const int hcolBase = (ho < 2) ? 0 : ((ho < 6) ? 256 : 512);

  for (int t = 0; t < T_STEPS; ++t) {
    // meas_t/60 -> ACT2[260..261] (disjoint from stage1's ACT2[0..255] writes)
    if (tid < 16) {
      float2 mm = *(const float2*)(x + ((size_t)(b0 + tid) << 8) + (t << 1));
      *(unsigned int*)(ACT2 + tid * KSTR + 260) = pack2(mm.x * (1.f / 60.f), mm.y * (1.f / 60.f));
    }
    // stage1: cu = tanh(Wm0 . [c, sn])
    stage_mm<2, 9>(PK1, B1, ACT1, KSTR, ACT2, KSTR, wave, 8, lane);
    __syncthreads();
    // stage2: t1|t2|th = tanh([Wf10|Wf20|Wh0] . [cu, sn, meas/60])
    stage_mm<6, 9>(PK2, B2, ACT2, KSTR, S2O, S2STR, wave, 8, lane);
    __syncthreads();
    // small heads: 128 (o,b) dots of length 256; 4 partial lanes each
    {
      const u16* ap = S2O + hb * S2STR + hcolBase + (hpart << 6);
      const u16* wp = HWs + (ho << 8) + (hpart << 6);
      float p = 0.f;
#pragma unroll
      for (int i = 0; i < 8; ++i) {
        bf16x8 av = *(const bf16x8*)(ap + (i << 3));
        bf16x8 wv = *(const bf16x8*)(wp + (i << 3));
#pragma unroll
        for (int j = 0; j < 8; ++j) p += (float)av[j] * (float)wv[j];
      }
      p += __shfl_xor(p, 1);
      p += __shfl_xor(p, 2);
      if (hpart == 0) SM[hb * 8 + ho] = clampf(p + BS[ho], -64.f, 64.f);
    }
    __syncthreads();
    // Kalman update (lane b owns batch row b; s,P fp32 registers)
    if (tid < 16) {
      const float* sm = SM + tid * 8;
      float d0 = sm[0], d1 = sm[1];
      float pv[4] = { sm[2], sm[3], sm[4], sm[5] };
      float hv0 = sm[6], hv1 = sm[7];
      float2 mm = *(const float2*)(x + ((size_t)(b0 + tid) << 8) + (t << 1));
      float m0 = mm.x, m1 = mm.y;
      float sp[4];
      sp[0] = s0v + s2v + 0.5f * d0;
      sp[1] = s1v + s3v + 0.5f * d1;
      sp[2] = s2v + d0;
      sp[3] = s3v + d1;
      float FP[16], Pp[16];
#pragma unroll
      for (int j = 0; j < 4; ++j) {
        FP[0 * 4 + j] = P[0 * 4 + j] + P[2 * 4 + j];
        FP[1 * 4 + j] = P[1 * 4 + j] + P[3 * 4 + j];
        FP[2 * 4 + j] = P[2 * 4 + j];
        FP[3 * 4 + j] = P[3 * 4 + j];
      }
#pragma unroll
      for (int i = 0; i < 4; ++i) {
        Pp[i * 4 + 0] = FP[i * 4 + 0] + FP[i * 4 + 2];
        Pp[i * 4 + 1] = FP[i * 4 + 1] + FP[i * 4 + 3];
        Pp[i * 4 + 2] = FP[i * 4 + 2];
        Pp[i * 4 + 3] = FP[i * 4 + 3];
      }
#pragma unroll
      for (int i = 0; i < 4; ++i)
#pragma unroll
        for (int j = 0; j < 4; ++j) Pp[i * 4 + j] += pv[i] * pv[j];
#pragma unroll
      for (int i = 0; i < 4; ++i) Pp[i * 4 + i] += 0.01f;
      float in0 = m0 - sp[0], in1 = m1 - sp[1];
      float S00 = Pp[0] + hv0 * hv0 + 1.0f;
      float S01 = Pp[1] + hv0 * hv1;
      float S10 = Pp[4] + hv1 * hv0;
      float S11 = Pp[5] + hv1 * hv1 + 1.0f;
      float det = S00 * S11 - S01 * S10;
      if (!(fabsf(det) > 1e-8f)) det = 1e-8f;
      float idet = 1.0f / det;
      float i00 =  S11 * idet, i01 = -S01 * idet, i10 = -S10 * idet, i11 = S00 * idet;
      float K[8], KS[8], su[4];
#pragma unroll
      for (int i = 0; i < 4; ++i) {
        K[i * 2 + 0] = Pp[i * 4 + 0] * i00 + Pp[i * 4 + 1] * i10;
        K[i * 2 + 1] = Pp[i * 4 + 0] * i01 + Pp[i * 4 + 1] * i11;
      }
#pragma unroll
      for (int i = 0; i < 4; ++i)
        su[i] = clampf(sp[i] + K[i * 2 + 0] * in0 + K[i * 2 + 1] * in1, -131072.f, 131072.f);
#pragma unroll
      for (int i = 0; i < 4; ++i) {
        KS[i * 2 + 0] = K[i * 2 + 0] * S00 + K[i * 2 + 1] * S10;
        KS[i * 2 + 1] = K[i * 2 + 0] * S01 + K[i * 2 + 1] * S11;
      }
#pragma unroll
      for (int i = 0; i < 4; ++i)
#pragma unroll
        for (int j = 0; j < 4; ++j)
          P[i * 4 + j] = clampf(
              Pp[i * 4 + j] - (KS[i * 2 + 0] * K[j * 2 + 0] + KS[i * 2 + 1] * K[j * 2 + 1]),
              -131072.f, 131072.f);
      s0v = su[0]; s1v = su[1]; s2v = su[2]; s3v = su[3];
      // emit output s_upd (f32)
      float4 ov; ov.x = su[0]; ov.y = su[1]; ov.z = su[2]; ov.w = su[3];
      *(float4*)(out + ((size_t)(b0 + tid) << 9) + (t << 2)) = ov;
      // next-step sn and this-step supd/60 (bf16)
      const float i60 = 1.0f / 60.0f;
      uint2 snp; snp.x = pack2(su[0] * i60, su[1] * i60); snp.y = pack2(su[2] * i60, su[3] * i60);
      *(uint2*)(ACT1 + tid * KSTR + 256) = snp;
      *(uint2*)(ACT2 + tid * KSTR + 256) = snp;
      *(uint2*)(ACT2 + tid * KSTR + 264) = snp;
    }
    __syncthreads();
    // stage3: c_new = tanh(Wm1 . [cu, meas/60, supd/60]) -> ACT1[:,0:256]
    stage_mm<2, 9>(PK3, B3, ACT2, KSTR, ACT1, KSTR, wave, 8, lane);
    __syncthreads();
  }
}

extern "C" void kernel_launch(void* const* d_in, const int* in_sizes, int n_in,
                              void* d_out, int out_size, void* d_ws, size_t ws_size,
                              hipStream_t stream) {
  const float* x    = (const float*)d_in[0];
  const float* tgt  = (const float*)d_in[1];
  const float* c0   = (const float*)d_in[2];
  const float* Wm0  = (const float*)d_in[3];
  const float* bm0  = (const float*)d_in[4];
  const float* Wm1  = (const float*)d_in[5];
  const float* bm1  = (const float*)d_in[6];
  const float* Wf10 = (const float*)d_in[7];
  const float* bf10 = (const float*)d_in[8];
  const float* Wf11 = (const float*)d_in[9];
  const float* bf11 = (const float*)d_in[10];
  const float* Wf20 = (const float*)d_in[11];
  const float* bf20 = (const float*)d_in[12];
  const float* Wf21 = (const float*)d_in[13];
  const float* bf21 = (const float*)d_in[14];
  const float* Wh0  = (const float*)d_in[15];
  const float* bh0  = (const float*)d_in[16];
  const float* Wh1  = (const float*)d_in[17];
  const float* bh1  = (const float*)d_in[18];
  u16* ws    = (u16*)d_ws;
  float* out = (float*)d_out;

  egbrnn_prep<<<dim3(1454), dim3(256), 0, stream>>>(
      Wm0, Wm1, Wf10, Wf11, Wf20, Wf21, Wh0, Wh1,
      bm0, bm1, bf10, bf11, bf20, bf21, bh0, bh1, ws);
  egbrnn_main<<<dim3(128), dim3(512), 0, stream>>>(x, tgt, c0, ws, out);
}